// Round 3
// baseline (587.969 us; speedup 1.0000x reference)
//
#include <hip/hip_runtime.h>
#include <stdint.h>

#define NROWS 32768   // B*H*W
#define CDIM  512
#define KCODES 1024
#define VC    512

typedef unsigned short u16;
typedef unsigned long long u64;
using bf16x8 = __attribute__((ext_vector_type(8))) __bf16;
using f32x4  = __attribute__((ext_vector_type(4))) float;

__device__ __forceinline__ float bf2f(u16 u){
  union { unsigned int i; float f; } x; x.i = ((unsigned int)u) << 16; return x.f;
}
__device__ __forceinline__ u16 f2bf(float f){
  union { float f; unsigned int i; } x; x.f = f;
  unsigned int u = x.i;
  u += 0x7fffu + ((u >> 16) & 1u);   // RNE
  return (u16)(u >> 16);
}
__device__ __forceinline__ unsigned int pack2(u16 lo, u16 hi){
  return (unsigned int)lo | ((unsigned int)hi << 16);
}
__device__ __forceinline__ unsigned int fkey(float f){
  unsigned int u = __float_as_uint(f);
  return (u & 0x80000000u) ? ~u : (u | 0x80000000u);   // monotone sortable
}
__device__ __forceinline__ f32x4 mfma16(bf16x8 a, bf16x8 b, f32x4 c){
  return __builtin_amdgcn_mfma_f32_16x16x32_bf16(a, b, c, 0, 0, 0);
}
// async global->LDS, 16B per lane; LDS dest is wave-uniform base + lane*16
__device__ __forceinline__ void gload_lds16(const void* g, void* l){
  __builtin_amdgcn_global_load_lds(
      (const __attribute__((address_space(1))) unsigned int*)g,
      (__attribute__((address_space(3))) unsigned int*)l, 16, 0, 0);
}

// ---------------- K1: transpose x (B,C,H,W) -> xf bf16 (N=32768, C=512) ---
__global__ __launch_bounds__(256) void k_transpose_x(const float* __restrict__ x,
                                                     u16* __restrict__ xf){
  __shared__ float tile[32][33];
  int b  = blockIdx.z;
  int p0 = blockIdx.x * 32;
  int c0 = blockIdx.y * 32;
  int tx = threadIdx.x, ty = threadIdx.y;   // (32, 8)
  const float* xb = x + (size_t)b * CDIM * 4096;
#pragma unroll
  for (int i = 0; i < 4; i++){
    int c = c0 + ty + i * 8;
    tile[ty + i * 8][tx] = xb[(size_t)c * 4096 + p0 + tx];
  }
  __syncthreads();
#pragma unroll
  for (int i = 0; i < 4; i++){
    int p = p0 + ty + i * 8;
    xf[((size_t)(b * 4096 + p)) * CDIM + c0 + tx] = f2bf(tile[tx][ty + i * 8]);
  }
}

// ---------------- K2: per-row 1/||x|| from xf bf16 ------------------------
__global__ __launch_bounds__(256) void k_rownorm(const u16* __restrict__ xf,
                                                 float* __restrict__ rinv){
  int row  = blockIdx.x * 4 + (threadIdx.x >> 6);
  int lane = threadIdx.x & 63;
  const uint4* p = (const uint4*)(xf + (size_t)row * CDIM);
  uint4 v = p[lane];
  unsigned int w[4] = {v.x, v.y, v.z, v.w};
  float s = 0.f;
#pragma unroll
  for (int i = 0; i < 4; i++){
    float a = bf2f((u16)(w[i] & 0xffffu));
    float b = bf2f((u16)(w[i] >> 16));
    s += a * a + b * b;
  }
#pragma unroll
  for (int off = 32; off; off >>= 1) s += __shfl_xor(s, off, 64);
  if (lane == 0) rinv[row] = 1.0f / fmaxf(sqrtf(s), 1e-12f);
}

// ---------------- K3: normalize noise_feature rows -> mn bf16 -------------
__global__ __launch_bounds__(256) void k_norm_rows(const float* __restrict__ in,
                                                   u16* __restrict__ out){
  int row  = blockIdx.x * 4 + (threadIdx.x >> 6);
  int lane = threadIdx.x & 63;
  const float* r = in + (size_t)row * CDIM;
  float v[8]; float s = 0.f;
#pragma unroll
  for (int i = 0; i < 8; i++){ v[i] = r[lane + i * 64]; s += v[i] * v[i]; }
#pragma unroll
  for (int off = 32; off; off >>= 1) s += __shfl_xor(s, off, 64);
  float inv = 1.0f / fmaxf(sqrtf(s), 1e-12f);
#pragma unroll
  for (int i = 0; i < 8; i++) out[(size_t)row * CDIM + lane + i * 64] = f2bf(v[i] * inv);
}

// ---------------- K3b: transpose std (1024,512) -> stdT bf16 (512,1024) ---
__global__ __launch_bounds__(256) void k_transpose_std(const float* __restrict__ sd,
                                                       u16* __restrict__ stdT){
  __shared__ float tile[32][33];
  int k0 = blockIdx.x * 32;
  int v0 = blockIdx.y * 32;
  int tx = threadIdx.x, ty = threadIdx.y;
#pragma unroll
  for (int i = 0; i < 4; i++)
    tile[ty + i * 8][tx] = sd[(size_t)(k0 + ty + i * 8) * VC + v0 + tx];
  __syncthreads();
#pragma unroll
  for (int i = 0; i < 4; i++)
    stdT[(size_t)(v0 + ty + i * 8) * KCODES + k0 + tx] = f2bf(tile[tx][ty + i * 8]);
}

// ---------------- K4: GEMM1 (xf @ mn^T) + packed atomicMax argmax ---------
__global__ __launch_bounds__(256) void k_gemm1_am(const u16* __restrict__ xf,
                                                  const u16* __restrict__ mn,
                                                  u64* __restrict__ packed){
  __shared__ __align__(16) u16 As[128 * 64];
  __shared__ __align__(16) u16 Bs[128 * 64];
  int tid  = threadIdx.x;
  int wave = tid >> 6, lane = tid & 63;
  int wr = wave >> 1, wc = wave & 1;
  int quad = lane >> 4, l15 = lane & 15;
  int c0 = blockIdx.x * 128, r0 = blockIdx.y * 128;

  int srow = lane >> 3, schunk = lane & 7;
  const u16* ag = xf + (size_t)(r0 + wave * 8 + srow) * CDIM + schunk * 8;
  const u16* bg = mn + (size_t)(c0 + wave * 8 + srow) * CDIM + schunk * 8;
  u16* adst = As + wave * 8 * 64;
  u16* bdst = Bs + wave * 8 * 64;

  f32x4 acc[4][4];
#pragma unroll
  for (int rt = 0; rt < 4; rt++)
#pragma unroll
    for (int ct = 0; ct < 4; ct++) acc[rt][ct] = (f32x4)(0.f);

  for (int k0 = 0; k0 < CDIM; k0 += 64){
#pragma unroll
    for (int i = 0; i < 4; i++){
      gload_lds16(ag + (size_t)i * 32 * CDIM + k0, adst + i * 32 * 64);
      gload_lds16(bg + (size_t)i * 32 * CDIM + k0, bdst + i * 32 * 64);
    }
    __syncthreads();
#pragma unroll
    for (int ks = 0; ks < 2; ks++){
      bf16x8 af[4], bfr[4];
#pragma unroll
      for (int rt = 0; rt < 4; rt++)
        af[rt] = *(const bf16x8*)(As + (wr * 64 + rt * 16 + l15) * 64 + ks * 32 + quad * 8);
#pragma unroll
      for (int ct = 0; ct < 4; ct++)
        bfr[ct] = *(const bf16x8*)(Bs + (wc * 64 + ct * 16 + l15) * 64 + ks * 32 + quad * 8);
#pragma unroll
      for (int rt = 0; rt < 4; rt++)
#pragma unroll
        for (int ct = 0; ct < 4; ct++)
          acc[rt][ct] = mfma16(af[rt], bfr[ct], acc[rt][ct]);
    }
    __syncthreads();
  }

#pragma unroll
  for (int rt = 0; rt < 4; rt++){
#pragma unroll
    for (int q = 0; q < 4; q++){
      float bv = acc[rt][0][q];
      int   bc = c0 + wc * 64 + l15;
#pragma unroll
      for (int ct = 1; ct < 4; ct++){
        float v = acc[rt][ct][q];
        int   c = c0 + wc * 64 + ct * 16 + l15;
        if (v > bv){ bv = v; bc = c; }          // ascending c: first wins ties
      }
#pragma unroll
      for (int off = 1; off <= 8; off <<= 1){
        float ov = __shfl_xor(bv, off, 64);
        int   oc = __shfl_xor(bc, off, 64);
        if (ov > bv || (ov == bv && oc < bc)){ bv = ov; bc = oc; }
      }
      if (l15 == 0){
        int rg = r0 + wr * 64 + rt * 16 + quad * 4 + q;
        u64 key = ((u64)fkey(bv) << 32) | (unsigned int)(~(unsigned int)bc);
        atomicMax(packed + rg, key);
      }
    }
  }
}

// ---------------- K5: per-code gather segment sum (reads packed directly) -
__global__ __launch_bounds__(256) void k_gather(const u64* __restrict__ packed,
                                                const u16* __restrict__ xf,
                                                float* __restrict__ esum,
                                                float* __restrict__ counts){
  __shared__ float part[4][CDIM];   // 8 KB
  __shared__ int   wcnt[4];
  int code = blockIdx.x;
  int tid = threadIdx.x, wave = tid >> 6, lane = tid & 63;
  float acc[8] = {0,0,0,0,0,0,0,0};
  int cnt = 0;
  for (int base = wave * 64; base < NROWS; base += 256){
    u64 pk = packed[base + lane];
    int cl = (int)(~(unsigned int)(pk & 0xffffffffull)) & (KCODES - 1);
    int match = (cl == code);
    u64 mask = __ballot(match);
    cnt += (int)__popcll(mask);
    while (mask){
      int b = __ffsll((long long)mask) - 1;
      mask &= mask - 1;
      int rr = base + b;
      uint4 v = *(const uint4*)(xf + (size_t)rr * CDIM + lane * 8);
      unsigned int w[4] = {v.x, v.y, v.z, v.w};
#pragma unroll
      for (int i = 0; i < 4; i++){
        acc[2 * i]     += bf2f((u16)(w[i] & 0xffffu));
        acc[2 * i + 1] += bf2f((u16)(w[i] >> 16));
      }
    }
  }
#pragma unroll
  for (int j = 0; j < 8; j++) part[wave][lane * 8 + j] = acc[j];
  if (lane == 0) wcnt[wave] = cnt;
  __syncthreads();
  for (int c = tid; c < CDIM; c += 256)
    esum[(size_t)code * CDIM + c] = part[0][c] + part[1][c] + part[2][c] + part[3][c];
  if (tid == 0) counts[code] = (float)(wcnt[0] + wcnt[1] + wcnt[2] + wcnt[3]);
}

// ---------------- K6: new_m = m*0.999 + mean*0.001; normalize -> mn2 bf16 -
__global__ __launch_bounds__(256) void k_newm(const float* __restrict__ m,
                                              const float* __restrict__ esum,
                                              const float* __restrict__ counts,
                                              u16* __restrict__ mn2){
  int row  = blockIdx.x * 4 + (threadIdx.x >> 6);
  int lane = threadIdx.x & 63;
  float cnt = counts[row];
  float sc  = 0.001f / (cnt + 1e-6f);
  float v[8]; float s = 0.f;
#pragma unroll
  for (int i = 0; i < 8; i++){
    int c = lane + i * 64;
    v[i] = m[(size_t)row * CDIM + c] * 0.999f + esum[(size_t)row * CDIM + c] * sc;
    s += v[i] * v[i];
  }
#pragma unroll
  for (int off = 32; off; off >>= 1) s += __shfl_xor(s, off, 64);
  float inv = 1.0f / fmaxf(sqrtf(s), 1e-12f);
#pragma unroll
  for (int i = 0; i < 8; i++) mn2[(size_t)row * CDIM + lane + i * 64] = f2bf(v[i] * inv);
}

// ---------------- K7: FUSED gemm2 + softmax + gemm3 (flash-style) v2 ------
// 64 rows/block, 512 thr, 16 tiles of 64 codes. As/Bs linear+XOR (gload_lds),
// Sf stride-68 f32, Pt stride-72 u16 (conflict-free), V read from global (L2).
// 3 barriers/tile; Bs(t+1) prefetch stays in flight across stats barrier.
#define NTILE 16
#define TCODE 64
__global__ __launch_bounds__(512) void k_fused(const u16* __restrict__ xf,
                                               const u16* __restrict__ mn2,
                                               const float* __restrict__ rinv,
                                               const u16* __restrict__ stdT,
                                               float* __restrict__ score2,
                                               float* __restrict__ out){
  __shared__ __align__(16) u16 As[64 * 512];     // 65536
  __shared__ __align__(16) u16 Bs[64 * 512];     // 65536
  __shared__ __align__(16) float Sf[64 * 68];    // 17408
  __shared__ __align__(16) u16 Pt[64 * 72];      // 9216
  __shared__ float rowm[64], rowl[64], rowsc[64];

  int tid  = threadIdx.x;
  int wave = tid >> 6, lane = tid & 63;
  int quad = lane >> 4, l15 = lane & 15;
  int r0 = blockIdx.x * 64;

  // S-phase: 8 waves as 2 row-groups x 4 col-groups; wave tile 32 rows x 16 codes
  int sR = (wave >> 2) * 32;          // row base within block
  int sC = (wave & 3) * 16;           // code base within tile
  int ar0 = sR + l15, ar1 = sR + 16 + l15;
  int br  = sC + l15;

  // PV: 8 waves as 2 x 4; wave tile 32 rows x 128 VC
  int R2 = (wave >> 2) * 32;
  int C2 = (wave & 3) * 128;

  // stats: 8 threads per row
  int srow = tid >> 3, ssub = tid & 7;
  float rv = rinv[r0 + srow];

  f32x4 acc[2][8];
#pragma unroll
  for (int rt = 0; rt < 2; rt++)
#pragma unroll
    for (int ct = 0; ct < 8; ct++) acc[rt][ct] = (f32x4)(0.f);

  // ---- prologue: stage As (once) + Bs(0) ----
#pragma unroll
  for (int i = 0; i < 8; i++){
    int rr = wave * 8 + i;
    gload_lds16(xf + (size_t)(r0 + rr) * CDIM + ((lane ^ (rr & 7)) * 8),
                As + rr * 512);
    gload_lds16(mn2 + (size_t)rr * CDIM + ((lane ^ (rr & 7)) * 8),
                Bs + rr * 512);
  }
  if (tid < 64){ rowm[tid] = -3.0e38f; rowl[tid] = 0.f; }
  asm volatile("s_waitcnt vmcnt(0)" ::: "memory");
  __builtin_amdgcn_s_barrier();

  for (int t = 0; t < NTILE; ++t){
    int kt = t * TCODE;
    // ---- S phase: wave computes 32x16 over K=512 ----
    f32x4 s0 = (f32x4)(0.f), s1 = (f32x4)(0.f);
#pragma unroll
    for (int ks = 0; ks < 16; ++ks){
      bf16x8 b  = *(const bf16x8*)(Bs + br * 512 + (((ks * 4 + quad) ^ (br & 7)) << 3));
      bf16x8 a0 = *(const bf16x8*)(As + ar0 * 512 + (((ks * 4 + quad) ^ (ar0 & 7)) << 3));
      bf16x8 a1 = *(const bf16x8*)(As + ar1 * 512 + (((ks * 4 + quad) ^ (ar1 & 7)) << 3));
      s0 = mfma16(a0, b, s0);
      s1 = mfma16(a1, b, s1);
    }
#pragma unroll
    for (int q = 0; q < 4; ++q){
      Sf[(sR + quad * 4 + q) * 68 + sC + l15]      = s0[q];
      Sf[(sR + 16 + quad * 4 + q) * 68 + sC + l15] = s1[q];
    }
    // B1: Sf visible; Bs(t) ds-reads complete
    asm volatile("s_waitcnt lgkmcnt(0)" ::: "memory");
    __builtin_amdgcn_s_barrier();
    // issue Bs(t+1) prefetch (stays in flight across stats phase)
    if (t + 1 < NTILE){
#pragma unroll
      for (int i = 0; i < 8; i++){
        int rr = wave * 8 + i;
        gload_lds16(mn2 + (size_t)(kt + TCODE + rr) * CDIM + ((lane ^ (rr & 7)) * 8),
                    Bs + rr * 512);
      }
    }
    // ---- stats: score2 write + online softmax + P(bf16) ----
    {
      f32x4 u = *(const f32x4*)(Sf + srow * 68 + ssub * 8);
      f32x4 w = *(const f32x4*)(Sf + srow * 68 + ssub * 8 + 4);
      u *= rv; w *= rv;
      float* so = score2 + (size_t)(r0 + srow) * KCODES + kt + ssub * 8;
      *(f32x4*)(so)     = u;
      *(f32x4*)(so + 4) = w;
      float mx = fmaxf(fmaxf(fmaxf(u[0], u[1]), fmaxf(u[2], u[3])),
                       fmaxf(fmaxf(w[0], w[1]), fmaxf(w[2], w[3])));
      mx = fmaxf(mx, __shfl_xor(mx, 1, 64));
      mx = fmaxf(mx, __shfl_xor(mx, 2, 64));
      mx = fmaxf(mx, __shfl_xor(mx, 4, 64));
      float mo = rowm[srow];
      float mn_ = fmaxf(mo, mx);
      float d = __expf(mo - mn_);
      float p[8];
#pragma unroll
      for (int j = 0; j < 4; j++){ p[j] = __expf(u[j] - mn_); p[4 + j] = __expf(w[j] - mn_); }
      float ss = 0.f;
#pragma unroll
      for (int j = 0; j < 8; j++) ss += p[j];
      ss += __shfl_xor(ss, 1, 64);
      ss += __shfl_xor(ss, 2, 64);
      ss += __shfl_xor(ss, 4, 64);
      if (ssub == 0){
        rowl[srow] = rowl[srow] * d + ss;
        rowm[srow] = mn_;
        rowsc[srow] = d;
      }
      uint4 pw;
      pw.x = pack2(f2bf(p[0]), f2bf(p[1]));
      pw.y = pack2(f2bf(p[2]), f2bf(p[3]));
      pw.z = pack2(f2bf(p[4]), f2bf(p[5]));
      pw.w = pack2(f2bf(p[6]), f2bf(p[7]));
      *(uint4*)(Pt + srow * 72 + ssub * 8) = pw;
    }
    // B2: Pt/rowsc visible (vmcnt NOT drained — Bs prefetch in flight)
    asm volatile("s_waitcnt lgkmcnt(0)" ::: "memory");
    __builtin_amdgcn_s_barrier();
    // ---- PV: rescale + accumulate; V frags straight from global (L2) ----
    bf16x8 vf[8][2];
#pragma unroll
    for (int ct = 0; ct < 8; ct++){
      const u16* vp = stdT + (size_t)(C2 + ct * 16 + l15) * KCODES + kt + quad * 8;
      vf[ct][0] = *(const bf16x8*)(vp);
      vf[ct][1] = *(const bf16x8*)(vp + 32);
    }
#pragma unroll
    for (int rt = 0; rt < 2; rt++)
#pragma unroll
      for (int q = 0; q < 4; q++){
        float s = rowsc[R2 + rt * 16 + quad * 4 + q];
#pragma unroll
        for (int ct = 0; ct < 8; ct++) acc[rt][ct][q] *= s;
      }
    bf16x8 pa[2][2];
#pragma unroll
    for (int rt = 0; rt < 2; rt++){
      int rr = R2 + rt * 16 + l15;
#pragma unroll
      for (int ks = 0; ks < 2; ks++)
        pa[rt][ks] = *(const bf16x8*)(Pt + rr * 72 + (ks * 4 + quad) * 8);
    }
#pragma unroll
    for (int ct = 0; ct < 8; ct++)
#pragma unroll
      for (int ks = 0; ks < 2; ks++)
#pragma unroll
        for (int rt = 0; rt < 2; rt++)
          acc[rt][ct] = mfma16(pa[rt][ks], vf[ct][ks], acc[rt][ct]);
    // B3: end of tile — drain Bs(t+1) prefetch before next S phase
    asm volatile("s_waitcnt vmcnt(0) lgkmcnt(0)" ::: "memory");
    __builtin_amdgcn_s_barrier();
  }

  // ---- epilogue: O /= rowsum ----
#pragma unroll
  for (int rt = 0; rt < 2; rt++)
#pragma unroll
    for (int q = 0; q < 4; q++){
      int rr = R2 + rt * 16 + quad * 4 + q;
      float inv = 1.0f / rowl[rr];
#pragma unroll
      for (int ct = 0; ct < 8; ct++)
        out[(size_t)(r0 + rr) * VC + C2 + ct * 16 + l15] = acc[rt][ct][q] * inv;
    }
}

// ---------------- launch ---------------------------------------------------
extern "C" void kernel_launch(void* const* d_in, const int* in_sizes, int n_in,
                              void* d_out, int out_size, void* d_ws, size_t ws_size,
                              hipStream_t stream){
  (void)in_sizes; (void)n_in; (void)out_size; (void)ws_size;
  const float* x      = (const float*)d_in[0];
  const float* m      = (const float*)d_in[1];
  const float* stdmat = (const float*)d_in[2];
  float* out    = (float*)d_out;
  float* score2 = out + (size_t)NROWS * VC;     // outputs: (out, score2)

  char* ws = (char*)d_ws;
  u16*   xf     = (u16*)  (ws + 0);             // 33,554,432 B
  u16*   mn     = (u16*)  (ws + 33554432);      //  1,048,576 B
  u16*   mn2    = (u16*)  (ws + 34603008);      //  1,048,576 B
  u16*   stdT   = (u16*)  (ws + 35651584);      //  1,048,576 B
  float* rinv   = (float*)(ws + 36700160);      //    131,072 B
  u64*   packed = (u64*)  (ws + 36831232);      //    262,144 B
  float* esum   = (float*)(ws + 37224448);      //  2,097,152 B
  float* counts = (float*)(ws + 39321600);      //      4,096 B

  hipMemsetAsync(packed, 0, (size_t)NROWS * 8, stream);  // key=0 is identity

  k_transpose_x  <<<dim3(128, 16, 8), dim3(32, 8), 0, stream>>>(x, xf);
  k_rownorm      <<<NROWS / 4, 256, 0, stream>>>(xf, rinv);
  k_norm_rows    <<<KCODES / 4, 256, 0, stream>>>(m, mn);
  k_transpose_std<<<dim3(32, 16), dim3(32, 8), 0, stream>>>(stdmat, stdT);
  k_gemm1_am     <<<dim3(KCODES / 128, NROWS / 128), 256, 0, stream>>>(xf, mn, packed);
  k_gather       <<<KCODES, 256, 0, stream>>>(packed, xf, esum, counts);
  k_newm         <<<KCODES / 4, 256, 0, stream>>>(m, esum, counts, mn2);
  k_fused        <<<NROWS / 64, 512, 0, stream>>>(xf, mn2, rinv, stdT, score2, out);
}

// Round 4
// 502.970 us; speedup vs baseline: 1.1690x; 1.1690x over previous
//
#include <hip/hip_runtime.h>
#include <stdint.h>

#define NROWS 32768   // B*H*W
#define CDIM  512
#define KCODES 1024
#define VC    512
#define LDP 72        // padded LDS leading dim (elements) — gemm3 A tile only

typedef unsigned short u16;
typedef unsigned long long u64;
using bf16x8 = __attribute__((ext_vector_type(8))) __bf16;
using f32x4  = __attribute__((ext_vector_type(4))) float;

__device__ __forceinline__ float bf2f(u16 u){
  union { unsigned int i; float f; } x; x.i = ((unsigned int)u) << 16; return x.f;
}
__device__ __forceinline__ u16 f2bf(float f){
  union { float f; unsigned int i; } x; x.f = f;
  unsigned int u = x.i;
  u += 0x7fffu + ((u >> 16) & 1u);   // RNE
  return (u16)(u >> 16);
}
__device__ __forceinline__ unsigned int pack2(u16 lo, u16 hi){
  return (unsigned int)lo | ((unsigned int)hi << 16);
}
__device__ __forceinline__ unsigned int fkey(float f){
  unsigned int u = __float_as_uint(f);
  return (u & 0x80000000u) ? ~u : (u | 0x80000000u);   // monotone sortable
}
__device__ __forceinline__ f32x4 mfma16(bf16x8 a, bf16x8 b, f32x4 c){
  return __builtin_amdgcn_mfma_f32_16x16x32_bf16(a, b, c, 0, 0, 0);
}
// async global->LDS, 16B per lane; LDS dest is wave-uniform base + lane*16
__device__ __forceinline__ void gload_lds16(const void* g, void* l){
  __builtin_amdgcn_global_load_lds(
      (const __attribute__((address_space(1))) unsigned int*)g,
      (__attribute__((address_space(3))) unsigned int*)l, 16, 0, 0);
}

// ---- K1: transpose x (B,C,H,W) -> xf bf16 (N, C); fused ||x||^2 partials -
// 64x64 tile, float4 loads, bf16x8 stores, XOR-swizzled LDS (col ^ (c&0x38)).
__global__ __launch_bounds__(256) void k_transpose_x(const float* __restrict__ x,
                                                     u16* __restrict__ xf,
                                                     float* __restrict__ rsum){
  __shared__ float tile[64 * 64];   // 16 KB, swizzled, no pad
  int b  = blockIdx.z;
  int p0 = blockIdx.x * 64;
  int c0 = blockIdx.y * 64;
  int t  = threadIdx.x;
  const float* xb = x + (size_t)b * CDIM * 4096 + (size_t)c0 * 4096 + p0;

  int pl4 = (t & 15) * 4;           // p offset for float4 load
#pragma unroll
  for (int i = 0; i < 4; i++){
    int cl = i * 16 + (t >> 4);
    float4 v = *(const float4*)(xb + (size_t)cl * 4096 + pl4);
    *(float4*)(tile + cl * 64 + (pl4 ^ (cl & 0x38))) = v;
  }
  __syncthreads();

  int cl0 = (t & 7) * 8;            // c base for this thread's 8 outputs
#pragma unroll
  for (int pass = 0; pass < 2; pass++){
    int pl = pass * 32 + (t >> 3);
    float v[8]; float s = 0.f;
#pragma unroll
    for (int j = 0; j < 8; j++){
      v[j] = tile[(cl0 + j) * 64 + (pl ^ cl0)];   // (cl0+j)&0x38 == cl0 for j<8
      s += v[j] * v[j];
    }
    uint4 o;
    o.x = pack2(f2bf(v[0]), f2bf(v[1]));
    o.y = pack2(f2bf(v[2]), f2bf(v[3]));
    o.z = pack2(f2bf(v[4]), f2bf(v[5]));
    o.w = pack2(f2bf(v[6]), f2bf(v[7]));
    *(uint4*)(xf + (size_t)(b * 4096 + p0 + pl) * CDIM + c0 + cl0) = o;
    // reduce s over the 8 lanes sharing this row (lane bits 0..2)
    s += __shfl_xor(s, 1, 64);
    s += __shfl_xor(s, 2, 64);
    s += __shfl_xor(s, 4, 64);
    if ((t & 7) == 0) atomicAdd(rsum + b * 4096 + p0 + pl, s);
  }
}

// ---- K2: rinv = 1/max(sqrt(rsum),1e-12) ----------------------------------
__global__ __launch_bounds__(256) void k_rinv_fin(const float* __restrict__ rsum,
                                                  float* __restrict__ rinv){
  int i = blockIdx.x * 256 + threadIdx.x;
  rinv[i] = 1.0f / fmaxf(sqrtf(rsum[i]), 1e-12f);
}

// ---------------- K3: normalize noise_feature rows -> mn bf16 -------------
__global__ __launch_bounds__(256) void k_norm_rows(const float* __restrict__ in,
                                                   u16* __restrict__ out){
  int row  = blockIdx.x * 4 + (threadIdx.x >> 6);
  int lane = threadIdx.x & 63;
  const float* r = in + (size_t)row * CDIM;
  float v[8]; float s = 0.f;
#pragma unroll
  for (int i = 0; i < 8; i++){ v[i] = r[lane + i * 64]; s += v[i] * v[i]; }
#pragma unroll
  for (int off = 32; off; off >>= 1) s += __shfl_xor(s, off, 64);
  float inv = 1.0f / fmaxf(sqrtf(s), 1e-12f);
#pragma unroll
  for (int i = 0; i < 8; i++) out[(size_t)row * CDIM + lane + i * 64] = f2bf(v[i] * inv);
}

// ---------------- K3b: transpose std (1024,512) -> stdT bf16 (512,1024) ---
__global__ __launch_bounds__(256) void k_transpose_std(const float* __restrict__ sd,
                                                       u16* __restrict__ stdT){
  __shared__ float tile[32][33];
  int k0 = blockIdx.x * 32;
  int v0 = blockIdx.y * 32;
  int tx = threadIdx.x, ty = threadIdx.y;
#pragma unroll
  for (int i = 0; i < 4; i++)
    tile[ty + i * 8][tx] = sd[(size_t)(k0 + ty + i * 8) * VC + v0 + tx];
  __syncthreads();
#pragma unroll
  for (int i = 0; i < 4; i++)
    stdT[(size_t)(v0 + ty + i * 8) * KCODES + k0 + tx] = f2bf(tile[tx][ty + i * 8]);
}

// ---------------- K4: GEMM1 (xf @ mn^T) + packed atomicMax argmax ---------
__global__ __launch_bounds__(256) void k_gemm1_am(const u16* __restrict__ xf,
                                                  const u16* __restrict__ mn,
                                                  u64* __restrict__ packed){
  __shared__ __align__(16) u16 As[128 * 64];
  __shared__ __align__(16) u16 Bs[128 * 64];
  int tid  = threadIdx.x;
  int wave = tid >> 6, lane = tid & 63;
  int wr = wave >> 1, wc = wave & 1;
  int quad = lane >> 4, l15 = lane & 15;
  int c0 = blockIdx.x * 128, r0 = blockIdx.y * 128;

  int srow = lane >> 3, schunk = lane & 7;
  const u16* ag = xf + (size_t)(r0 + wave * 8 + srow) * CDIM + schunk * 8;
  const u16* bg = mn + (size_t)(c0 + wave * 8 + srow) * CDIM + schunk * 8;
  u16* adst = As + wave * 8 * 64;
  u16* bdst = Bs + wave * 8 * 64;

  f32x4 acc[4][4];
#pragma unroll
  for (int rt = 0; rt < 4; rt++)
#pragma unroll
    for (int ct = 0; ct < 4; ct++) acc[rt][ct] = (f32x4)(0.f);

  for (int k0 = 0; k0 < CDIM; k0 += 64){
#pragma unroll
    for (int i = 0; i < 4; i++){
      gload_lds16(ag + (size_t)i * 32 * CDIM + k0, adst + i * 32 * 64);
      gload_lds16(bg + (size_t)i * 32 * CDIM + k0, bdst + i * 32 * 64);
    }
    __syncthreads();
#pragma unroll
    for (int ks = 0; ks < 2; ks++){
      bf16x8 af[4], bfr[4];
#pragma unroll
      for (int rt = 0; rt < 4; rt++)
        af[rt] = *(const bf16x8*)(As + (wr * 64 + rt * 16 + l15) * 64 + ks * 32 + quad * 8);
#pragma unroll
      for (int ct = 0; ct < 4; ct++)
        bfr[ct] = *(const bf16x8*)(Bs + (wc * 64 + ct * 16 + l15) * 64 + ks * 32 + quad * 8);
#pragma unroll
      for (int rt = 0; rt < 4; rt++)
#pragma unroll
        for (int ct = 0; ct < 4; ct++)
          acc[rt][ct] = mfma16(af[rt], bfr[ct], acc[rt][ct]);
    }
    __syncthreads();
  }

#pragma unroll
  for (int rt = 0; rt < 4; rt++){
#pragma unroll
    for (int q = 0; q < 4; q++){
      float bv = acc[rt][0][q];
      int   bc = c0 + wc * 64 + l15;
#pragma unroll
      for (int ct = 1; ct < 4; ct++){
        float v = acc[rt][ct][q];
        int   c = c0 + wc * 64 + ct * 16 + l15;
        if (v > bv){ bv = v; bc = c; }          // ascending c: first wins ties
      }
#pragma unroll
      for (int off = 1; off <= 8; off <<= 1){
        float ov = __shfl_xor(bv, off, 64);
        int   oc = __shfl_xor(bc, off, 64);
        if (ov > bv || (ov == bv && oc < bc)){ bv = ov; bc = oc; }
      }
      if (l15 == 0){
        int rg = r0 + wr * 64 + rt * 16 + quad * 4 + q;
        u64 key = ((u64)fkey(bv) << 32) | (unsigned int)(~(unsigned int)bc);
        atomicMax(packed + rg, key);
      }
    }
  }
}

// ---------------- K5: per-code gather segment sum (reads packed directly) -
__global__ __launch_bounds__(256) void k_gather(const u64* __restrict__ packed,
                                                const u16* __restrict__ xf,
                                                float* __restrict__ esum,
                                                float* __restrict__ counts){
  __shared__ float part[4][CDIM];   // 8 KB
  __shared__ int   wcnt[4];
  int code = blockIdx.x;
  int tid = threadIdx.x, wave = tid >> 6, lane = tid & 63;
  float acc[8] = {0,0,0,0,0,0,0,0};
  int cnt = 0;
  for (int base = wave * 64; base < NROWS; base += 256){
    u64 pk = packed[base + lane];
    int cl = (int)(~(unsigned int)(pk & 0xffffffffull)) & (KCODES - 1);
    int match = (cl == code);
    u64 mask = __ballot(match);
    cnt += (int)__popcll(mask);
    while (mask){
      int b = __ffsll((long long)mask) - 1;
      mask &= mask - 1;
      int rr = base + b;
      uint4 v = *(const uint4*)(xf + (size_t)rr * CDIM + lane * 8);
      unsigned int w[4] = {v.x, v.y, v.z, v.w};
#pragma unroll
      for (int i = 0; i < 4; i++){
        acc[2 * i]     += bf2f((u16)(w[i] & 0xffffu));
        acc[2 * i + 1] += bf2f((u16)(w[i] >> 16));
      }
    }
  }
#pragma unroll
  for (int j = 0; j < 8; j++) part[wave][lane * 8 + j] = acc[j];
  if (lane == 0) wcnt[wave] = cnt;
  __syncthreads();
  for (int c = tid; c < CDIM; c += 256)
    esum[(size_t)code * CDIM + c] = part[0][c] + part[1][c] + part[2][c] + part[3][c];
  if (tid == 0) counts[code] = (float)(wcnt[0] + wcnt[1] + wcnt[2] + wcnt[3]);
}

// ---------------- K6: new_m = m*0.999 + mean*0.001; normalize -> mn2 bf16 -
__global__ __launch_bounds__(256) void k_newm(const float* __restrict__ m,
                                              const float* __restrict__ esum,
                                              const float* __restrict__ counts,
                                              u16* __restrict__ mn2){
  int row  = blockIdx.x * 4 + (threadIdx.x >> 6);
  int lane = threadIdx.x & 63;
  float cnt = counts[row];
  float sc  = 0.001f / (cnt + 1e-6f);
  float v[8]; float s = 0.f;
#pragma unroll
  for (int i = 0; i < 8; i++){
    int c = lane + i * 64;
    v[i] = m[(size_t)row * CDIM + c] * 0.999f + esum[(size_t)row * CDIM + c] * sc;
    s += v[i] * v[i];
  }
#pragma unroll
  for (int off = 32; off; off >>= 1) s += __shfl_xor(s, off, 64);
  float inv = 1.0f / fmaxf(sqrtf(s), 1e-12f);
#pragma unroll
  for (int i = 0; i < 8; i++) mn2[(size_t)row * CDIM + lane + i * 64] = f2bf(v[i] * inv);
}

// ---------------- K7: GEMM2 score2 = (xf @ mn2^T) * rinv[row] -------------
// + fused per-(row, 64-col) softmax partials: pmax/psum (16 partials/row)
__global__ __launch_bounds__(256) void k_gemm2(const u16* __restrict__ xf,
                                               const u16* __restrict__ mn2,
                                               const float* __restrict__ rinv,
                                               float* __restrict__ score2,
                                               float* __restrict__ pmax,
                                               float* __restrict__ psum){
  __shared__ __align__(16) u16 As[128 * 64];
  __shared__ __align__(16) u16 Bs[128 * 64];
  int tid  = threadIdx.x;
  int wave = tid >> 6, lane = tid & 63;
  int wr = wave >> 1, wc = wave & 1;
  int quad = lane >> 4, l15 = lane & 15;
  int c0 = blockIdx.x * 128, r0 = blockIdx.y * 128;

  int srow = lane >> 3, schunk = lane & 7;
  const u16* ag = xf  + (size_t)(r0 + wave * 8 + srow) * CDIM + schunk * 8;
  const u16* bg = mn2 + (size_t)(c0 + wave * 8 + srow) * CDIM + schunk * 8;
  u16* adst = As + wave * 8 * 64;
  u16* bdst = Bs + wave * 8 * 64;

  f32x4 acc[4][4];
#pragma unroll
  for (int rt = 0; rt < 4; rt++)
#pragma unroll
    for (int ct = 0; ct < 4; ct++) acc[rt][ct] = (f32x4)(0.f);

  for (int k0 = 0; k0 < CDIM; k0 += 64){
#pragma unroll
    for (int i = 0; i < 4; i++){
      gload_lds16(ag + (size_t)i * 32 * CDIM + k0, adst + i * 32 * 64);
      gload_lds16(bg + (size_t)i * 32 * CDIM + k0, bdst + i * 32 * 64);
    }
    __syncthreads();
#pragma unroll
    for (int ks = 0; ks < 2; ks++){
      bf16x8 af[4], bfr[4];
#pragma unroll
      for (int rt = 0; rt < 4; rt++)
        af[rt] = *(const bf16x8*)(As + (wr * 64 + rt * 16 + l15) * 64 + ks * 32 + quad * 8);
#pragma unroll
      for (int ct = 0; ct < 4; ct++)
        bfr[ct] = *(const bf16x8*)(Bs + (wc * 64 + ct * 16 + l15) * 64 + ks * 32 + quad * 8);
#pragma unroll
      for (int rt = 0; rt < 4; rt++)
#pragma unroll
        for (int ct = 0; ct < 4; ct++)
          acc[rt][ct] = mfma16(af[rt], bfr[ct], acc[rt][ct]);
    }
    __syncthreads();
  }

#pragma unroll
  for (int rt = 0; rt < 4; rt++){
#pragma unroll
    for (int q = 0; q < 4; q++){
      int grow = r0 + wr * 64 + rt * 16 + quad * 4 + q;
      float rv = rinv[grow];
      float v0 = acc[rt][0][q] * rv;
      float v1 = acc[rt][1][q] * rv;
      float v2 = acc[rt][2][q] * rv;
      float v3 = acc[rt][3][q] * rv;
      float* so = score2 + (size_t)grow * KCODES + c0 + wc * 64 + l15;
      so[0]  = v0;
      so[16] = v1;
      so[32] = v2;
      so[48] = v3;
      float mx = fmaxf(fmaxf(v0, v1), fmaxf(v2, v3));
#pragma unroll
      for (int off = 1; off <= 8; off <<= 1) mx = fmaxf(mx, __shfl_xor(mx, off, 64));
      float s = __expf(v0 - mx) + __expf(v1 - mx) + __expf(v2 - mx) + __expf(v3 - mx);
#pragma unroll
      for (int off = 1; off <= 8; off <<= 1) s += __shfl_xor(s, off, 64);
      if (l15 == 0){
        int pi = grow * 16 + blockIdx.x * 2 + wc;
        pmax[pi] = mx;
        psum[pi] = s;
      }
    }
  }
}

// ---------------- K8: combine 16 partials/row -> rowmax, rsinv ------------
__global__ __launch_bounds__(256) void k_softcomb(const float* __restrict__ pmax,
                                                  const float* __restrict__ psum,
                                                  float* __restrict__ rowmax,
                                                  float* __restrict__ rsinv){
  int row = blockIdx.x * 256 + threadIdx.x;
  const float* pm = pmax + (size_t)row * 16;
  const float* ps = psum + (size_t)row * 16;
  float M = pm[0];
#pragma unroll
  for (int i = 1; i < 16; i++) M = fmaxf(M, pm[i]);
  float S = 0.f;
#pragma unroll
  for (int i = 0; i < 16; i++) S += ps[i] * __expf(pm[i] - M);
  rowmax[row] = M;
  rsinv[row]  = 1.0f / S;
}

// ---------------- K9: out = softmax(score2) @ std  (128x256 tile, 512 thr)
// B tile linear [256][64] via global_load_lds; A tile reg-staged (exp) padded
__global__ __launch_bounds__(512) void k_gemm3(const float* __restrict__ score2,
                                               const float* __restrict__ rowmax,
                                               const float* __restrict__ rsinv,
                                               const u16* __restrict__ stdT,
                                               float* __restrict__ out){
  __shared__ __align__(16) u16 As[128 * LDP];   // 18 KB, padded (ds_write side)
  __shared__ __align__(16) u16 Bs[256 * 64];    // 32 KB, linear (global_load_lds)
  int tid  = threadIdx.x;
  int wave = tid >> 6, lane = tid & 63;
  int wr = wave >> 2, wcol = wave & 3;          // 2 x 4 wave grid
  int quad = lane >> 4, l15 = lane & 15;
  int c0 = blockIdx.x * 256, r0 = blockIdx.y * 128;
  int arow = tid >> 2, aq = tid & 3;            // A: 4 thr/row, 16 elems each

  int srow = lane >> 3, schunk = lane & 7;
  const u16* bg = stdT + (size_t)(c0 + wave * 8 + srow) * KCODES + schunk * 8;
  u16* bdst = Bs + wave * 8 * 64;

  float rmax = rowmax[r0 + arow];
  float rs   = rsinv [r0 + arow];

  f32x4 acc[4][4];
#pragma unroll
  for (int rt = 0; rt < 4; rt++)
#pragma unroll
    for (int ct = 0; ct < 4; ct++) acc[rt][ct] = (f32x4)(0.f);

  const float* ag = score2 + (size_t)(r0 + arow) * KCODES + aq * 16;

  for (int k0 = 0; k0 < KCODES; k0 += 64){
#pragma unroll
    for (int i = 0; i < 4; i++)
      gload_lds16(bg + (size_t)i * 64 * KCODES + k0, bdst + i * 64 * 64);
#pragma unroll
    for (int j = 0; j < 2; j++){
      float4 a = *(const float4*)(ag + k0 + j * 8);
      float4 b = *(const float4*)(ag + k0 + j * 8 + 4);
      uint4 o;
      o.x = pack2(f2bf(__expf(a.x - rmax) * rs), f2bf(__expf(a.y - rmax) * rs));
      o.y = pack2(f2bf(__expf(a.z - rmax) * rs), f2bf(__expf(a.w - rmax) * rs));
      o.z = pack2(f2bf(__expf(b.x - rmax) * rs), f2bf(__expf(b.y - rmax) * rs));
      o.w = pack2(f2bf(__expf(b.z - rmax) * rs), f2bf(__expf(b.w - rmax) * rs));
      *(uint4*)(As + arow * LDP + aq * 16 + j * 8) = o;
    }
    __syncthreads();
#pragma unroll
    for (int ks = 0; ks < 2; ks++){
      bf16x8 af[4], bfr[4];
#pragma unroll
      for (int rt = 0; rt < 4; rt++)
        af[rt] = *(const bf16x8*)(As + (wr * 64 + rt * 16 + l15) * LDP + ks * 32 + quad * 8);
#pragma unroll
      for (int ct = 0; ct < 4; ct++)
        bfr[ct] = *(const bf16x8*)(Bs + (wcol * 64 + ct * 16 + l15) * 64 + ks * 32 + quad * 8);
#pragma unroll
      for (int rt = 0; rt < 4; rt++)
#pragma unroll
        for (int ct = 0; ct < 4; ct++)
          acc[rt][ct] = mfma16(af[rt], bfr[ct], acc[rt][ct]);
    }
    __syncthreads();
  }
#pragma unroll
  for (int rt = 0; rt < 4; rt++){
#pragma unroll
    for (int q = 0; q < 4; q++){
      int grow = r0 + wr * 64 + rt * 16 + quad * 4 + q;
#pragma unroll
      for (int ct = 0; ct < 4; ct++){
        int gcol = c0 + wcol * 64 + ct * 16 + l15;
        out[(size_t)grow * VC + gcol] = acc[rt][ct][q];
      }
    }
  }
}

// ---------------- launch ---------------------------------------------------
extern "C" void kernel_launch(void* const* d_in, const int* in_sizes, int n_in,
                              void* d_out, int out_size, void* d_ws, size_t ws_size,
                              hipStream_t stream){
  (void)in_sizes; (void)n_in; (void)out_size; (void)ws_size;
  const float* x      = (const float*)d_in[0];
  const float* m      = (const float*)d_in[1];
  const float* stdmat = (const float*)d_in[2];
  float* out    = (float*)d_out;
  float* score2 = out + (size_t)NROWS * VC;     // outputs: (out, score2)

  char* ws = (char*)d_ws;
  u16*   xf     = (u16*)  (ws + 0);             // 33,554,432 B
  u16*   mn     = (u16*)  (ws + 33554432);      //  1,048,576 B
  u16*   mn2    = (u16*)  (ws + 34603008);      //  1,048,576 B
  u16*   stdT   = (u16*)  (ws + 35651584);      //  1,048,576 B
  float* rinv   = (float*)(ws + 36700160);      //    131,072 B
  u64*   packed = (u64*)  (ws + 36831232);      //    262,144 B
  float* esum   = (float*)(ws + 37224448);      //  2,097,152 B
  float* counts = (float*)(ws + 39321600);      //      4,096 B
  float* rowmax = (float*)(ws + 39325696);      //    131,072 B (aliased: rsum early)
  float* rsinv  = (float*)(ws + 39456768);      //    131,072 B
  float* pmax   = (float*)(ws + 39587840);      //  2,097,152 B
  float* psum   = (float*)(ws + 41684992);      //  2,097,152 B
  float* rsum   = rowmax;                       // disjoint lifetime: rsum dead
                                                // before k_softcomb writes rowmax

  hipMemsetAsync(packed, 0, (size_t)NROWS * 8, stream);  // key=0 is identity
  hipMemsetAsync(rsum,   0, (size_t)NROWS * 4, stream);

  k_transpose_x  <<<dim3(64, 8, 8), 256, 0, stream>>>(x, xf, rsum);
  k_rinv_fin     <<<NROWS / 256, 256, 0, stream>>>(rsum, rinv);
  k_norm_rows    <<<KCODES / 4, 256, 0, stream>>>(m, mn);
  k_transpose_std<<<dim3(32, 16), dim3(32, 8), 0, stream>>>(stdmat, stdT);
  k_gemm1_am     <<<dim3(KCODES / 128, NROWS / 128), 256, 0, stream>>>(xf, mn, packed);
  k_gather       <<<KCODES, 256, 0, stream>>>(packed, xf, esum, counts);
  k_newm         <<<KCODES / 4, 256, 0, stream>>>(m, esum, counts, mn2);
  k_gemm2        <<<dim3(KCODES / 128, NROWS / 128), 256, 0, stream>>>(xf, mn2, rinv, score2, pmax, psum);
  k_softcomb     <<<NROWS / 256, 256, 0, stream>>>(pmax, psum, rowmax, rsinv);
  k_gemm3        <<<dim3(VC / 256, NROWS / 128), 512, 0, stream>>>(score2, rowmax, rsinv, stdT, out);
}